// Round 7
// baseline (451.164 us; speedup 1.0000x reference)
//
#include <hip/hip_runtime.h>
#include <hip/hip_bf16.h>
#include <stdint.h>

#define B_ 4
#define T_ 2048
#define D_ 1024
#define M_ (B_*T_)
#define NH_ 16
#define HD_ 64

typedef __attribute__((ext_vector_type(8))) short bf16x8;
typedef __attribute__((ext_vector_type(4))) float f32x4;

// async global->LDS, 16B per lane; LDS dest = wave-uniform base + lane*16
#define GLOAD_LDS16(gp, lp)                                                   \
  __builtin_amdgcn_global_load_lds(                                           \
      (const __attribute__((address_space(1))) void*)(gp),                    \
      (__attribute__((address_space(3))) void*)(lp), 16, 0, 0)

__device__ __forceinline__ unsigned short f2bf(float f) {
  union { float f; unsigned u; } x; x.f = f;
  unsigned r = x.u + 0x7FFFu + ((x.u >> 16) & 1u);
  return (unsigned short)(r >> 16);
}

// ---------------- convert x (f32 -> bf16) ----------------
__global__ __launch_bounds__(256) void cvt_x_kernel(const float* __restrict__ x,
                                                    unsigned short* __restrict__ xb) {
  int i = (blockIdx.x * 256 + threadIdx.x) * 8;
  float4 a = *(const float4*)(x + i);
  float4 b = *(const float4*)(x + i + 4);
  ushort4 lo, hi;
  lo.x = f2bf(a.x); lo.y = f2bf(a.y); lo.z = f2bf(a.z); lo.w = f2bf(a.w);
  hi.x = f2bf(b.x); hi.y = f2bf(b.y); hi.z = f2bf(b.z); hi.w = f2bf(b.w);
  *(ushort4*)(xb + i) = lo;
  *(ushort4*)(xb + i + 4) = hi;
}

// ---------------- transpose all 4 W [K][N] f32 -> Wt [N][K] bf16 (grid.y selects) ----
__global__ __launch_bounds__(256) void transpose_w4_kernel(
    const float* __restrict__ W0, const float* __restrict__ W1,
    const float* __restrict__ W2, const float* __restrict__ W3,
    unsigned short* __restrict__ O0, unsigned short* __restrict__ O1,
    unsigned short* __restrict__ O2, unsigned short* __restrict__ O3) {
  const float* W = (blockIdx.y == 0) ? W0 : (blockIdx.y == 1) ? W1 : (blockIdx.y == 2) ? W2 : W3;
  unsigned short* Wt = (blockIdx.y == 0) ? O0 : (blockIdx.y == 1) ? O1 : (blockIdx.y == 2) ? O2 : O3;
  __shared__ unsigned short tile[64][72];
  const int bk = (blockIdx.x & 15) * 64;
  const int bn = (blockIdx.x >> 4) * 64;
  const int t = threadIdx.x;
  const int r0 = t >> 4;
  const int c0 = (t & 15) * 4;
#pragma unroll
  for (int p = 0; p < 4; ++p) {
    int r = p * 16 + r0;
    float4 v = *(const float4*)&W[(size_t)(bk + r) * D_ + bn + c0];
    tile[r][c0 + 0] = f2bf(v.x);
    tile[r][c0 + 1] = f2bf(v.y);
    tile[r][c0 + 2] = f2bf(v.z);
    tile[r][c0 + 3] = f2bf(v.w);
  }
  __syncthreads();
#pragma unroll
  for (int p = 0; p < 4; ++p) {
    int n = p * 16 + r0;
    ushort4 o;
    o.x = tile[c0 + 0][n];
    o.y = tile[c0 + 1][n];
    o.z = tile[c0 + 2][n];
    o.w = tile[c0 + 3][n];
    *(ushort4*)&Wt[(size_t)(bn + n) * D_ + bk + c0] = o;
  }
}

// ---------------- transpose V (bf16) per batch: Vtg[b][c][t] = Vb[b][t][c] ----------
// grid: (16, 32, 4)  -> (c-tile, t-tile, b)
__global__ __launch_bounds__(256) void transpose_v_kernel(
    const unsigned short* __restrict__ Vb, unsigned short* __restrict__ Vtg) {
  __shared__ unsigned short tile[64][72];
  const int ct = blockIdx.x * 64;
  const int tt = blockIdx.y * 64;
  const size_t bofs_in  = (size_t)blockIdx.z * T_ * D_;
  const size_t bofs_out = (size_t)blockIdx.z * D_ * T_;
  const int t = threadIdx.x;
  const int r0 = t >> 4;
  const int c0 = (t & 15) * 4;
#pragma unroll
  for (int p = 0; p < 4; ++p) {
    int r = p * 16 + r0;   // t-within
    *(ushort4*)&tile[r][c0] = *(const ushort4*)&Vb[bofs_in + (size_t)(tt + r) * D_ + ct + c0];
  }
  __syncthreads();
#pragma unroll
  for (int p = 0; p < 4; ++p) {
    int n = p * 16 + r0;   // c-within (output row)
    ushort4 o;
    o.x = tile[c0 + 0][n];
    o.y = tile[c0 + 1][n];
    o.z = tile[c0 + 2][n];
    o.w = tile[c0 + 3][n];
    *(ushort4*)&Vtg[bofs_out + (size_t)(ct + n) * T_ + tt + c0] = o;
  }
}

// ---------------- GEMM core (m97 structure): linear LDS + global_load_lds ----------
#define BM 128
#define BN 128
#define BK 64
template <typename OutT>
__device__ __forceinline__ void gemm_core(
    const unsigned short* __restrict__ A, const unsigned short* __restrict__ Bt,
    const float* __restrict__ bias, OutT* __restrict__ C,
    unsigned short* As, unsigned short* Bs, int bm, int bn) {
  const int K = D_, N = D_;
  const int t = threadIdx.x;
  const int lane = t & 63;
  const int w = t >> 6;
  const int wr = (w >> 1) * 64;
  const int wc = (w & 1) * 64;
  const int lr = lane & 15;
  const int lk = (lane >> 4) * 8;
  const int cr = (lane >> 4) * 4;
  const int cc = lane & 15;
  const int srow = lane >> 3;
  const int scol = (lane & 7) * 8;

  f32x4 acc[4][4] = {};

  for (int k0 = 0; k0 < K; k0 += BK) {
#pragma unroll
    for (int i = 0; i < 4; ++i) {
      const int rbase = w * 32 + i * 8;
      GLOAD_LDS16(&A[(size_t)(bm + rbase + srow) * K + k0 + scol], &As[rbase * BK]);
      GLOAD_LDS16(&Bt[(size_t)(bn + rbase + srow) * K + k0 + scol], &Bs[rbase * BK]);
    }
    __syncthreads();
#pragma unroll
    for (int kk = 0; kk < BK; kk += 32) {
      bf16x8 a[4], b[4];
#pragma unroll
      for (int m = 0; m < 4; ++m) a[m] = *(const bf16x8*)&As[(wr + m * 16 + lr) * BK + kk + lk];
#pragma unroll
      for (int n = 0; n < 4; ++n) b[n] = *(const bf16x8*)&Bs[(wc + n * 16 + lr) * BK + kk + lk];
#pragma unroll
      for (int m = 0; m < 4; ++m)
#pragma unroll
        for (int n = 0; n < 4; ++n)
          acc[m][n] = __builtin_amdgcn_mfma_f32_16x16x32_bf16(a[m], b[n], acc[m][n], 0, 0, 0);
    }
    __syncthreads();
  }

#pragma unroll
  for (int m = 0; m < 4; ++m)
#pragma unroll
    for (int n = 0; n < 4; ++n) {
      int col = bn + wc + n * 16 + cc;
      float bv = bias[col];
#pragma unroll
      for (int j = 0; j < 4; ++j) {
        int row = bm + wr + m * 16 + cr + j;
        float v = acc[m][n][j] + bv;
        if constexpr (__is_same(OutT, float)) {
          C[(size_t)row * N + col] = v;
        } else {
          C[(size_t)row * N + col] = f2bf(v);
        }
      }
    }
}

// fused QKV: grid (8, 64, 3); XCD swizzle: all n-blocks+z of an A-panel on one XCD
__global__ __launch_bounds__(256) void gemm_qkv_kernel(
    const unsigned short* __restrict__ xb,
    const unsigned short* __restrict__ WqT, const unsigned short* __restrict__ WkT,
    const unsigned short* __restrict__ WvT,
    const float* __restrict__ bq, const float* __restrict__ bk, const float* __restrict__ bv,
    unsigned short* __restrict__ Qb, unsigned short* __restrict__ Kb,
    unsigned short* __restrict__ Vb) {
  __shared__ unsigned short As[BM * BK];
  __shared__ unsigned short Bs[BN * BK];
  const int z = blockIdx.z;
  const unsigned short* Bt = (z == 0) ? WqT : (z == 1) ? WkT : WvT;
  const float* bias = (z == 0) ? bq : (z == 1) ? bk : bv;
  unsigned short* C = (z == 0) ? Qb : (z == 1) ? Kb : Vb;
  // XCD = blockIdx.x (hw round-robin on linear id). A-panel index depends only on x.
  const int by = blockIdx.x * 8 + (blockIdx.y & 7);   // A-panel (m-block)
  const int bx = blockIdx.y >> 3;                     // n-block
  gemm_core<unsigned short>(xb, Bt, bias, C, As, Bs, by * BM, bx * BN);
}

__global__ __launch_bounds__(256) void gemm_proj_kernel(
    const unsigned short* __restrict__ A, const unsigned short* __restrict__ Bt,
    const float* __restrict__ bias, float* __restrict__ C) {
  __shared__ unsigned short As[BM * BK];
  __shared__ unsigned short Bs[BN * BK];
  const int by = blockIdx.x * 8 + (blockIdx.y & 7);
  const int bx = blockIdx.y >> 3;
  gemm_core<float>(A, Bt, bias, C, As, Bs, by * BM, bx * BN);
}

// ---------------- flash attention (causal), no K/V LDS staging, no barriers ---------
// grid: (8, 64), 512 threads. bh = x*8 + (y&7) (XCD-local heads); pid = y>>3.
// Block handles q-tiles {pid, 15-pid}; wave w owns 16 q-rows [qtile+w*16, +16).
__global__ __launch_bounds__(512) void attn_kernel(
    const unsigned short* __restrict__ Qb,
    const unsigned short* __restrict__ Kb,
    const unsigned short* __restrict__ Vtg,   // [B][D][T] per-batch transposed V
    unsigned short* __restrict__ Ob)
{
  __shared__ unsigned int Ps32[8][16][36];   // per-wave P rows (bf16 pairs), stride 144B

  const int bh = blockIdx.x * 8 + (blockIdx.y & 7);
  const int pid = blockIdx.y >> 3;
  const int b = bh >> 4, h = bh & 15;
  const int t = threadIdx.x;
  const int lane = t & 63;
  const int w = t >> 6;            // 0..7
  const int lr = lane & 15;        // q-row within subtile (S^T col); also frag row
  const int g = lane >> 4;
  const int lk = g * 8;
  const int cr = g * 4;
  const int cc = lane & 15;

  const size_t base  = (size_t)(b * T_) * D_ + h * HD_;    // Q/K/O rows
  const size_t vbase = ((size_t)b * D_ + h * HD_) * T_;    // Vtg rows (d-major)

  for (int hp = 0; hp < 2; ++hp) {
    const int qtile = (hp == 0 ? pid : 15 - pid) * 128;
    const int qrow0 = qtile + w * 16;

    // Q fragments (B-operand)
    bf16x8 qf[2];
#pragma unroll
    for (int kk = 0; kk < 2; ++kk)
      qf[kk] = *(const bf16x8*)&Qb[base + (size_t)(qrow0 + lr) * D_ + kk * 32 + lk];

    f32x4 acc_o[4] = {};
    float mrun = -1e30f, lrun = 0.f;

    const int kvend_w = qtile + ((w >> 2) + 1) * 64;   // per-wave causal end
    for (int kvb = 0; kvb < kvend_w; kvb += 64) {
      // S^T = K Q^T : s[n] lane holds (q=lr, k=n*16+g*4+j), direct global K reads
      f32x4 s[4] = {};
#pragma unroll
      for (int kk = 0; kk < 2; ++kk) {
#pragma unroll
        for (int n = 0; n < 4; ++n) {
          bf16x8 kf = *(const bf16x8*)&Kb[base + (size_t)(kvb + n * 16 + lr) * D_ + kk * 32 + lk];
          s[n] = __builtin_amdgcn_mfma_f32_16x16x32_bf16(kf, qf[kk], s[n], 0, 0, 0);
        }
      }

      const int qi = qrow0 + lr;   // this lane's q-row
      if (kvb + 63 > qrow0) {      // diagonal: mask ki > qi
#pragma unroll
        for (int n = 0; n < 4; ++n)
#pragma unroll
          for (int j = 0; j < 4; ++j) {
            int ki = kvb + n * 16 + cr + j;
            if (ki > qi) s[n][j] = -1e30f;
          }
      }

      // row max (16 in-lane + xor16 + xor32)
      float tmax = -1e30f;
#pragma unroll
      for (int n = 0; n < 4; ++n)
        tmax = fmaxf(tmax, fmaxf(fmaxf(s[n][0], s[n][1]), fmaxf(s[n][2], s[n][3])));
      tmax = fmaxf(tmax, __shfl_xor(tmax, 16));
      tmax = fmaxf(tmax, __shfl_xor(tmax, 32));

      // defer-max (T13): rescale only when some row grew > 8
      float sc = 1.f;
      if (!__all(tmax <= mrun + 8.f)) {
        float mnew = fmaxf(mrun, tmax);
        sc = __expf(mrun - mnew);
        mrun = mnew;
#pragma unroll
        for (int j = 0; j < 4; ++j) {
          float scj = __shfl(sc, (lane & 48) | (cr + j));
#pragma unroll
          for (int n = 0; n < 4; ++n) acc_o[n][j] *= scj;
        }
      }

      float psum = 0.f;
#pragma unroll
      for (int n = 0; n < 4; ++n)
#pragma unroll
        for (int j = 0; j < 4; ++j) {
          float p = __expf(s[n][j] - mrun);
          s[n][j] = p;
          psum += p;
        }
      psum += __shfl_xor(psum, 16);
      psum += __shfl_xor(psum, 32);
      lrun = lrun * sc + psum;

      // pack P pairs -> per-wave LDS (conflict-light u32 writes)
#pragma unroll
      for (int n = 0; n < 4; ++n)
#pragma unroll
        for (int hh = 0; hh < 2; ++hh) {
          float lo = s[n][2 * hh], hi = s[n][2 * hh + 1];
          unsigned pk;
          asm("v_cvt_pk_bf16_f32 %0, %1, %2" : "=v"(pk) : "v"(lo), "v"(hi));
          Ps32[w][lr][n * 8 + g * 2 + hh] = pk;
        }

      // O += P V : pa = A-frag of P; vf = B-frag direct from Vtg (d-major rows)
#pragma unroll
      for (int kk = 0; kk < 2; ++kk) {
        bf16x8 pa = *(const bf16x8*)((const unsigned short*)&Ps32[w][lr][0] + kk * 32 + lk);
#pragma unroll
        for (int n = 0; n < 4; ++n) {
          bf16x8 vf = *(const bf16x8*)&Vtg[vbase + (size_t)(n * 16 + lr) * T_ + kvb + kk * 32 + lk];
          acc_o[n] = __builtin_amdgcn_mfma_f32_16x16x32_bf16(pa, vf, acc_o[n], 0, 0, 0);
        }
      }
    }

    // epilogue: rows cr+j, cols n*16+cc
#pragma unroll
    for (int j = 0; j < 4; ++j) {
      float inv = 1.0f / __shfl(lrun, (lane & 48) | (cr + j));
#pragma unroll
      for (int n = 0; n < 4; ++n)
        Ob[base + (size_t)(qrow0 + cr + j) * D_ + n * 16 + cc] = f2bf(acc_o[n][j] * inv);
    }
  }
}

// ---------------- launch ----------------
extern "C" void kernel_launch(void* const* d_in, const int* in_sizes, int n_in,
                              void* d_out, int out_size, void* d_ws, size_t ws_size,
                              hipStream_t stream) {
  const float* x  = (const float*)d_in[0];
  const float* Wk = (const float*)d_in[1];
  const float* bk = (const float*)d_in[2];
  const float* Wq = (const float*)d_in[3];
  const float* bq = (const float*)d_in[4];
  const float* Wv = (const float*)d_in[5];
  const float* bv = (const float*)d_in[6];
  const float* Wp = (const float*)d_in[7];
  const float* bp = (const float*)d_in[8];

  char* ws = (char*)d_ws;
  unsigned short* xb  = (unsigned short*)(ws);            // 16MB; Ob aliases after use
  unsigned short* Ob  = (unsigned short*)(ws);
  unsigned short* WqT = (unsigned short*)(ws + (16ull << 20));
  unsigned short* WkT = (unsigned short*)(ws + (18ull << 20));
  unsigned short* WvT = (unsigned short*)(ws + (20ull << 20));
  unsigned short* WpT = (unsigned short*)(ws + (22ull << 20));
  unsigned short* Qb  = (unsigned short*)(ws + (24ull << 20));
  unsigned short* Kb  = (unsigned short*)(ws + (40ull << 20));
  unsigned short* Vb  = (unsigned short*)(ws + (56ull << 20));
  unsigned short* Vtg = (unsigned short*)(ws + (72ull << 20));  // 16MB -> 88MB total

  hipLaunchKernelGGL(cvt_x_kernel, dim3((M_ * D_) / (256 * 8)), dim3(256), 0, stream, x, xb);
  hipLaunchKernelGGL(transpose_w4_kernel, dim3(256, 4), dim3(256), 0, stream,
                     Wq, Wk, Wv, Wp, WqT, WkT, WvT, WpT);

  hipLaunchKernelGGL(gemm_qkv_kernel, dim3(D_ / BN, M_ / BM, 3), dim3(256), 0, stream,
                     xb, WqT, WkT, WvT, bq, bk, bv, Qb, Kb, Vb);

  hipLaunchKernelGGL(transpose_v_kernel, dim3(16, 32, 4), dim3(256), 0, stream, Vb, Vtg);

  hipLaunchKernelGGL(attn_kernel, dim3(8, 64), dim3(512), 0, stream, Qb, Kb, Vtg, Ob);

  hipLaunchKernelGGL(gemm_proj_kernel, dim3(D_ / BN, M_ / BM), dim3(256), 0, stream,
                     Ob, WpT, bp, (float*)d_out);
}

// Round 8
// 293.228 us; speedup vs baseline: 1.5386x; 1.5386x over previous
//
#include <hip/hip_runtime.h>
#include <hip/hip_bf16.h>
#include <stdint.h>

#define B_ 4
#define T_ 2048
#define D_ 1024
#define M_ (B_*T_)
#define NH_ 16
#define HD_ 64

typedef __attribute__((ext_vector_type(8))) short bf16x8;
typedef __attribute__((ext_vector_type(4))) float f32x4;

// async global->LDS, 16B per lane; LDS dest = wave-uniform base + lane*16
#define GLOAD_LDS16(gp, lp)                                                   \
  __builtin_amdgcn_global_load_lds(                                           \
      (const __attribute__((address_space(1))) void*)(gp),                    \
      (__attribute__((address_space(3))) void*)(lp), 16, 0, 0)

__device__ __forceinline__ unsigned short f2bf(float f) {
  union { float f; unsigned u; } x; x.f = f;
  unsigned r = x.u + 0x7FFFu + ((x.u >> 16) & 1u);
  return (unsigned short)(r >> 16);
}

// ---------------- convert x (f32 -> bf16) ----------------
__global__ __launch_bounds__(256) void cvt_x_kernel(const float* __restrict__ x,
                                                    unsigned short* __restrict__ xb) {
  int i = (blockIdx.x * 256 + threadIdx.x) * 8;
  float4 a = *(const float4*)(x + i);
  float4 b = *(const float4*)(x + i + 4);
  ushort4 lo, hi;
  lo.x = f2bf(a.x); lo.y = f2bf(a.y); lo.z = f2bf(a.z); lo.w = f2bf(a.w);
  hi.x = f2bf(b.x); hi.y = f2bf(b.y); hi.z = f2bf(b.z); hi.w = f2bf(b.w);
  *(ushort4*)(xb + i) = lo;
  *(ushort4*)(xb + i + 4) = hi;
}

// ---------------- transpose all 4 W [K][N] f32 -> Wt [N][K] bf16 (grid.y selects) ----
__global__ __launch_bounds__(256) void transpose_w4_kernel(
    const float* __restrict__ W0, const float* __restrict__ W1,
    const float* __restrict__ W2, const float* __restrict__ W3,
    unsigned short* __restrict__ O0, unsigned short* __restrict__ O1,
    unsigned short* __restrict__ O2, unsigned short* __restrict__ O3) {
  const float* W = (blockIdx.y == 0) ? W0 : (blockIdx.y == 1) ? W1 : (blockIdx.y == 2) ? W2 : W3;
  unsigned short* Wt = (blockIdx.y == 0) ? O0 : (blockIdx.y == 1) ? O1 : (blockIdx.y == 2) ? O2 : O3;
  __shared__ unsigned short tile[64][72];
  const int bk = (blockIdx.x & 15) * 64;
  const int bn = (blockIdx.x >> 4) * 64;
  const int t = threadIdx.x;
  const int r0 = t >> 4;
  const int c0 = (t & 15) * 4;
#pragma unroll
  for (int p = 0; p < 4; ++p) {
    int r = p * 16 + r0;
    float4 v = *(const float4*)&W[(size_t)(bk + r) * D_ + bn + c0];
    tile[r][c0 + 0] = f2bf(v.x);
    tile[r][c0 + 1] = f2bf(v.y);
    tile[r][c0 + 2] = f2bf(v.z);
    tile[r][c0 + 3] = f2bf(v.w);
  }
  __syncthreads();
#pragma unroll
  for (int p = 0; p < 4; ++p) {
    int n = p * 16 + r0;
    ushort4 o;
    o.x = tile[c0 + 0][n];
    o.y = tile[c0 + 1][n];
    o.z = tile[c0 + 2][n];
    o.w = tile[c0 + 3][n];
    *(ushort4*)&Wt[(size_t)(bn + n) * D_ + bk + c0] = o;
  }
}

// ---------------- transpose V (bf16) per batch: Vtg[b][c][t] = Vb[b][t][c] ----------
// grid: (16, 32, 4)  -> (c-tile, t-tile, b)
__global__ __launch_bounds__(256) void transpose_v_kernel(
    const unsigned short* __restrict__ Vb, unsigned short* __restrict__ Vtg) {
  __shared__ unsigned short tile[64][72];
  const int ct = blockIdx.x * 64;
  const int tt = blockIdx.y * 64;
  const size_t bofs_in  = (size_t)blockIdx.z * T_ * D_;
  const size_t bofs_out = (size_t)blockIdx.z * D_ * T_;
  const int t = threadIdx.x;
  const int r0 = t >> 4;
  const int c0 = (t & 15) * 4;
#pragma unroll
  for (int p = 0; p < 4; ++p) {
    int r = p * 16 + r0;   // t-within
    *(ushort4*)&tile[r][c0] = *(const ushort4*)&Vb[bofs_in + (size_t)(tt + r) * D_ + ct + c0];
  }
  __syncthreads();
#pragma unroll
  for (int p = 0; p < 4; ++p) {
    int n = p * 16 + r0;   // c-within (output row)
    ushort4 o;
    o.x = tile[c0 + 0][n];
    o.y = tile[c0 + 1][n];
    o.z = tile[c0 + 2][n];
    o.w = tile[c0 + 3][n];
    *(ushort4*)&Vtg[bofs_out + (size_t)(ct + n) * T_ + tt + c0] = o;
  }
}

// ---------------- GEMM core (m97 structure): linear LDS + global_load_lds ----------
#define BM 128
#define BN 128
#define BK 64
template <typename OutT>
__device__ __forceinline__ void gemm_core(
    const unsigned short* __restrict__ A, const unsigned short* __restrict__ Bt,
    const float* __restrict__ bias, OutT* __restrict__ C,
    unsigned short* As, unsigned short* Bs, int bm, int bn) {
  const int K = D_, N = D_;
  const int t = threadIdx.x;
  const int lane = t & 63;
  const int w = t >> 6;
  const int wr = (w >> 1) * 64;
  const int wc = (w & 1) * 64;
  const int lr = lane & 15;
  const int lk = (lane >> 4) * 8;
  const int cr = (lane >> 4) * 4;
  const int cc = lane & 15;
  const int srow = lane >> 3;
  const int scol = (lane & 7) * 8;

  f32x4 acc[4][4] = {};

  for (int k0 = 0; k0 < K; k0 += BK) {
#pragma unroll
    for (int i = 0; i < 4; ++i) {
      const int rbase = w * 32 + i * 8;
      GLOAD_LDS16(&A[(size_t)(bm + rbase + srow) * K + k0 + scol], &As[rbase * BK]);
      GLOAD_LDS16(&Bt[(size_t)(bn + rbase + srow) * K + k0 + scol], &Bs[rbase * BK]);
    }
    __syncthreads();
#pragma unroll
    for (int kk = 0; kk < BK; kk += 32) {
      bf16x8 a[4], b[4];
#pragma unroll
      for (int m = 0; m < 4; ++m) a[m] = *(const bf16x8*)&As[(wr + m * 16 + lr) * BK + kk + lk];
#pragma unroll
      for (int n = 0; n < 4; ++n) b[n] = *(const bf16x8*)&Bs[(wc + n * 16 + lr) * BK + kk + lk];
#pragma unroll
      for (int m = 0; m < 4; ++m)
#pragma unroll
        for (int n = 0; n < 4; ++n)
          acc[m][n] = __builtin_amdgcn_mfma_f32_16x16x32_bf16(a[m], b[n], acc[m][n], 0, 0, 0);
    }
    __syncthreads();
  }

#pragma unroll
  for (int m = 0; m < 4; ++m)
#pragma unroll
    for (int n = 0; n < 4; ++n) {
      int col = bn + wc + n * 16 + cc;
      float bv = bias[col];
#pragma unroll
      for (int j = 0; j < 4; ++j) {
        int row = bm + wr + m * 16 + cr + j;
        float v = acc[m][n][j] + bv;
        if constexpr (__is_same(OutT, float)) {
          C[(size_t)row * N + col] = v;
        } else {
          C[(size_t)row * N + col] = f2bf(v);
        }
      }
    }
}

// fused QKV: grid (8, 64, 3); XCD swizzle: all n-blocks+z of an A-panel on one XCD
__global__ __launch_bounds__(256) void gemm_qkv_kernel(
    const unsigned short* __restrict__ xb,
    const unsigned short* __restrict__ WqT, const unsigned short* __restrict__ WkT,
    const unsigned short* __restrict__ WvT,
    const float* __restrict__ bq, const float* __restrict__ bk, const float* __restrict__ bv,
    unsigned short* __restrict__ Qb, unsigned short* __restrict__ Kb,
    unsigned short* __restrict__ Vb) {
  __shared__ unsigned short As[BM * BK];
  __shared__ unsigned short Bs[BN * BK];
  const int z = blockIdx.z;
  const unsigned short* Bt = (z == 0) ? WqT : (z == 1) ? WkT : WvT;
  const float* bias = (z == 0) ? bq : (z == 1) ? bk : bv;
  unsigned short* C = (z == 0) ? Qb : (z == 1) ? Kb : Vb;
  const int by = blockIdx.x * 8 + (blockIdx.y & 7);   // A-panel (m-block)
  const int bx = blockIdx.y >> 3;                     // n-block
  gemm_core<unsigned short>(xb, Bt, bias, C, As, Bs, by * BM, bx * BN);
}

__global__ __launch_bounds__(256) void gemm_proj_kernel(
    const unsigned short* __restrict__ A, const unsigned short* __restrict__ Bt,
    const float* __restrict__ bias, float* __restrict__ C) {
  __shared__ unsigned short As[BM * BK];
  __shared__ unsigned short Bs[BN * BK];
  const int by = blockIdx.x * 8 + (blockIdx.y & 7);
  const int bx = blockIdx.y >> 3;
  gemm_core<float>(A, Bt, bias, C, As, Bs, by * BM, bx * BN);
}

// ---------------- flash attention (causal): LDS-staged K/V, 8 waves, T14 split ------
// grid: (8, 64), 512 threads. Block pid handles q-tiles {pid, 15-pid} (128 rows each);
// wave w owns 16 q-rows. Staging: next tile's K/V issued to regs right after barrier B,
// in flight during compute, drained by next iter's syncthreads (free).
__global__ __launch_bounds__(512, 4) void attn_kernel(
    const unsigned short* __restrict__ Qb,
    const unsigned short* __restrict__ Kb,
    const unsigned short* __restrict__ Vtg,   // [B][D][T] per-batch transposed V
    unsigned short* __restrict__ Ob)
{
  __shared__ unsigned short Ks[64][72];
  __shared__ unsigned short Vt[64][72];
  __shared__ unsigned int   Ps32[8][16][36];  // per-wave P rows (bf16 pairs)

  const int pid = blockIdx.x;      // 0..7
  const int bh  = blockIdx.y;      // 0..63
  const int b = bh >> 4, h = bh & 15;
  const int t = threadIdx.x;
  const int lane = t & 63;
  const int w = t >> 6;            // 0..7
  const int lr = lane & 15;        // q-row within wave's subtile (S^T col)
  const int g = lane >> 4;
  const int lk = g * 8;
  const int cr = g * 4;
  const int cc = lane & 15;

  const size_t base  = (size_t)(b * T_) * D_ + h * HD_;    // Q/K/O rows
  const size_t vbase = ((size_t)b * D_ + h * HD_) * T_;    // Vtg rows (d-major)

  // staging: thread t covers row sr, 8-short chunk scc (1 int4 per tensor)
  const int sr  = t >> 3;          // 0..63
  const int scc = (t & 7) * 8;     // 0..56

  // prologue: issue loads for kv tile 0
  int4 kreg = *(const int4*)&Kb[base + (size_t)sr * D_ + scc];
  int4 vreg = *(const int4*)&Vtg[vbase + (size_t)sr * T_ + scc];

  for (int hp = 0; hp < 2; ++hp) {
    const int qt = (hp == 0) ? pid : 15 - pid;
    const int qtile = qt * 128;
    const int qrow0 = qtile + w * 16;
    const int niter = 2 * qt + 2;

    bf16x8 qf[2];
#pragma unroll
    for (int kk = 0; kk < 2; ++kk)
      qf[kk] = *(const bf16x8*)&Qb[base + (size_t)(qrow0 + lr) * D_ + kk * 32 + lk];

    f32x4 acc_o[4] = {};
    float mrun = -1e30f, lrun = 0.f;

    for (int it = 0; it < niter; ++it) {
      const int kvb = it * 64;
      __syncthreads();                       // A: everyone done with previous tile
      *(int4*)&Ks[sr][scc] = kreg;
      *(int4*)&Vt[sr][scc] = vreg;
      __syncthreads();                       // B: writes visible
      // T14: issue next tile's loads now; they fly during compute below
      {
        int nkvb = (it + 1 < niter) ? (it + 1) * 64 : ((hp == 0) ? 0 : -1);
        if (nkvb >= 0) {
          kreg = *(const int4*)&Kb[base + (size_t)(nkvb + sr) * D_ + scc];
          vreg = *(const int4*)&Vtg[vbase + (size_t)sr * T_ + nkvb + scc];
        }
      }

      if (kvb <= qrow0 + 15) {               // wave-uniform: skip fully-masked tiles
        // S^T = K Q^T : lane holds (q = lr, k = n*16 + g*4 + j)
        f32x4 s[4] = {};
#pragma unroll
        for (int kk = 0; kk < 2; ++kk) {
          bf16x8 kf[4];
#pragma unroll
          for (int n = 0; n < 4; ++n) kf[n] = *(const bf16x8*)&Ks[n * 16 + lr][kk * 32 + lk];
#pragma unroll
          for (int n = 0; n < 4; ++n)
            s[n] = __builtin_amdgcn_mfma_f32_16x16x32_bf16(kf[n], qf[kk], s[n], 0, 0, 0);
        }

        const int qi = qrow0 + lr;
        if (kvb + 63 > qrow0) {              // diagonal tile: mask ki > qi
#pragma unroll
          for (int n = 0; n < 4; ++n)
#pragma unroll
            for (int j = 0; j < 4; ++j) {
              int ki = kvb + n * 16 + cr + j;
              if (ki > qi) s[n][j] = -1e30f;
            }
        }

        // row max (16 in-lane + xor16 + xor32)
        float tmax = -1e30f;
#pragma unroll
        for (int n = 0; n < 4; ++n)
          tmax = fmaxf(tmax, fmaxf(fmaxf(s[n][0], s[n][1]), fmaxf(s[n][2], s[n][3])));
        tmax = fmaxf(tmax, __shfl_xor(tmax, 16));
        tmax = fmaxf(tmax, __shfl_xor(tmax, 32));

        // defer-max (T13): rescale only when some row grew > 8
        float sc = 1.f;
        if (!__all(tmax <= mrun + 8.f)) {
          float mnew = fmaxf(mrun, tmax);
          sc = __expf(mrun - mnew);
          mrun = mnew;
#pragma unroll
          for (int j = 0; j < 4; ++j) {
            float scj = __shfl(sc, (lane & 48) | (cr + j));
#pragma unroll
            for (int n = 0; n < 4; ++n) acc_o[n][j] *= scj;
          }
        }

        float psum = 0.f;
#pragma unroll
        for (int n = 0; n < 4; ++n)
#pragma unroll
          for (int j = 0; j < 4; ++j) {
            float p = __expf(s[n][j] - mrun);
            s[n][j] = p;
            psum += p;
          }
        psum += __shfl_xor(psum, 16);
        psum += __shfl_xor(psum, 32);
        lrun = lrun * sc + psum;

        // pack P pairs -> per-wave LDS
#pragma unroll
        for (int n = 0; n < 4; ++n)
#pragma unroll
          for (int hh = 0; hh < 2; ++hh) {
            float lo = s[n][2 * hh], hi = s[n][2 * hh + 1];
            unsigned pk;
            asm("v_cvt_pk_bf16_f32 %0, %1, %2" : "=v"(pk) : "v"(lo), "v"(hi));
            Ps32[w][lr][n * 8 + g * 2 + hh] = pk;
          }

        // O += P V
#pragma unroll
        for (int kk = 0; kk < 2; ++kk) {
          bf16x8 pa = *(const bf16x8*)((const unsigned short*)&Ps32[w][lr][0] + kk * 32 + lk);
#pragma unroll
          for (int n = 0; n < 4; ++n) {
            bf16x8 vf = *(const bf16x8*)&Vt[n * 16 + lr][kk * 32 + lk];
            acc_o[n] = __builtin_amdgcn_mfma_f32_16x16x32_bf16(pa, vf, acc_o[n], 0, 0, 0);
          }
        }
      }
    }

    // epilogue: rows cr+j, cols n*16+cc
#pragma unroll
    for (int j = 0; j < 4; ++j) {
      float inv = 1.0f / __shfl(lrun, (lane & 48) | (cr + j));
#pragma unroll
      for (int n = 0; n < 4; ++n)
        Ob[base + (size_t)(qrow0 + cr + j) * D_ + n * 16 + cc] = f2bf(acc_o[n][j] * inv);
    }
  }
}

// ---------------- launch ----------------
extern "C" void kernel_launch(void* const* d_in, const int* in_sizes, int n_in,
                              void* d_out, int out_size, void* d_ws, size_t ws_size,
                              hipStream_t stream) {
  const float* x  = (const float*)d_in[0];
  const float* Wk = (const float*)d_in[1];
  const float* bk = (const float*)d_in[2];
  const float* Wq = (const float*)d_in[3];
  const float* bq = (const float*)d_in[4];
  const float* Wv = (const float*)d_in[5];
  const float* bv = (const float*)d_in[6];
  const float* Wp = (const float*)d_in[7];
  const float* bp = (const float*)d_in[8];

  char* ws = (char*)d_ws;
  unsigned short* xb  = (unsigned short*)(ws);            // 16MB; Ob aliases after use
  unsigned short* Ob  = (unsigned short*)(ws);
  unsigned short* WqT = (unsigned short*)(ws + (16ull << 20));
  unsigned short* WkT = (unsigned short*)(ws + (18ull << 20));
  unsigned short* WvT = (unsigned short*)(ws + (20ull << 20));
  unsigned short* WpT = (unsigned short*)(ws + (22ull << 20));
  unsigned short* Qb  = (unsigned short*)(ws + (24ull << 20));
  unsigned short* Kb  = (unsigned short*)(ws + (40ull << 20));
  unsigned short* Vb  = (unsigned short*)(ws + (56ull << 20));
  unsigned short* Vtg = (unsigned short*)(ws + (72ull << 20));  // 16MB -> 88MB total

  hipLaunchKernelGGL(cvt_x_kernel, dim3((M_ * D_) / (256 * 8)), dim3(256), 0, stream, x, xb);
  hipLaunchKernelGGL(transpose_w4_kernel, dim3(256, 4), dim3(256), 0, stream,
                     Wq, Wk, Wv, Wp, WqT, WkT, WvT, WpT);

  hipLaunchKernelGGL(gemm_qkv_kernel, dim3(D_ / BN, M_ / BM, 3), dim3(256), 0, stream,
                     xb, WqT, WkT, WvT, bq, bk, bv, Qb, Kb, Vb);

  hipLaunchKernelGGL(transpose_v_kernel, dim3(16, 32, 4), dim3(256), 0, stream, Vb, Vtg);

  hipLaunchKernelGGL(attn_kernel, dim3(8, 64), dim3(512), 0, stream, Qb, Kb, Vtg, Ob);

  hipLaunchKernelGGL(gemm_proj_kernel, dim3(D_ / BN, M_ / BM), dim3(256), 0, stream,
                     Ob, WpT, bp, (float*)d_out);
}